// Round 1
// baseline (966.069 us; speedup 1.0000x reference)
//
#include <hip/hip_runtime.h>
#include <hip/hip_bf16.h>
#include <math.h>

// Problem constants
#define PB 16      // batches
#define PN 32768   // points
#define PD 256     // point feature dim
#define PE 512     // embed dim
#define PH 8       // heads
#define PK 512     // top-k
#define PT 16      // output tokens
#define DH 64      // head dim

typedef __attribute__((ext_vector_type(8))) short bf16x8;
typedef __attribute__((ext_vector_type(4))) float f32x4;

// ---------------------------------------------------------------------------
// Kernel 1: per-batch top-512 (radix select on monotone u32 keys) + bitonic
// sort by (key desc, idx asc) so first 16 match jax.lax.top_k ordering.
// ---------------------------------------------------------------------------
__global__ __launch_bounds__(512) void topk_kernel(const float* __restrict__ scores,
                                                   int* __restrict__ sorted_idx) {
    const int b = blockIdx.x;
    const int tid = threadIdx.x;
    const int NT = 512;
    const float* s = scores + (size_t)b * PN;

    __shared__ unsigned int hist[256];
    __shared__ unsigned int sh_prefix;
    __shared__ int sh_remaining;
    __shared__ unsigned int sh_cnt_gt, sh_cnt_eq;
    __shared__ unsigned long long comp[PK];
    __shared__ unsigned int eq_idx[PK];

    unsigned int prefix = 0;
    int remaining = PK;
    for (int shift = 24; shift >= 0; shift -= 8) {
        for (int i = tid; i < 256; i += NT) hist[i] = 0;
        __syncthreads();
        for (int i = tid; i < PN; i += NT) {
            unsigned int u = __float_as_uint(s[i]);
            u = (u & 0x80000000u) ? ~u : (u | 0x80000000u);
            bool ok = (shift == 24) || ((u >> (shift + 8)) == prefix);
            if (ok) atomicAdd(&hist[(u >> shift) & 0xFFu], 1u);
        }
        __syncthreads();
        if (tid == 0) {
            int cum = 0;
            int d = 255;
            for (; d >= 0; --d) {
                cum += (int)hist[d];
                if (cum >= remaining) break;
            }
            sh_remaining = remaining - (cum - (int)hist[d]);
            sh_prefix = (prefix << 8) | (unsigned)d;
        }
        __syncthreads();
        prefix = sh_prefix;
        remaining = sh_remaining;
        __syncthreads();
    }
    const unsigned int TKEY = prefix;

    if (tid == 0) { sh_cnt_gt = 0; sh_cnt_eq = 0; }
    __syncthreads();
    for (int i = tid; i < PN; i += NT) {
        unsigned int u = __float_as_uint(s[i]);
        u = (u & 0x80000000u) ? ~u : (u | 0x80000000u);
        if (u > TKEY) {
            unsigned p = atomicAdd(&sh_cnt_gt, 1u);
            comp[p] = ((unsigned long long)u << 32) | (unsigned int)(~(unsigned)i);
        } else if (u == TKEY) {
            unsigned p = atomicAdd(&sh_cnt_eq, 1u);
            if (p < PK) eq_idx[p] = (unsigned)i;
        }
    }
    __syncthreads();
    const int cnt_gt = (int)sh_cnt_gt;
    const int need_eq = PK - cnt_gt;
    const int ec = (int)sh_cnt_eq < PK ? (int)sh_cnt_eq : PK;
    if (tid == 0) {
        for (int j = 0; j < need_eq; ++j) {
            unsigned mv = 0xFFFFFFFFu; int mb = 0;
            for (int i2 = 0; i2 < ec; ++i2)
                if (eq_idx[i2] < mv) { mv = eq_idx[i2]; mb = i2; }
            comp[cnt_gt + j] = ((unsigned long long)TKEY << 32) | (unsigned int)(~mv);
            eq_idx[mb] = 0xFFFFFFFFu;
        }
    }
    __syncthreads();

    // bitonic sort, descending (key desc; tie -> ~idx larger = idx smaller first)
    for (unsigned ksz = 2; ksz <= PK; ksz <<= 1) {
        for (unsigned j = ksz >> 1; j > 0; j >>= 1) {
            unsigned i = (unsigned)tid;
            unsigned ixj = i ^ j;
            if (ixj > i && i < PK) {
                unsigned long long a = comp[i], c = comp[ixj];
                bool sw = ((i & ksz) == 0) ? (a < c) : (a > c);
                if (sw) { comp[i] = c; comp[ixj] = a; }
            }
            __syncthreads();
        }
    }
    if (tid < PK)
        sorted_idx[b * PK + tid] = (int)(~(unsigned int)(comp[tid] & 0xFFFFFFFFull));
}

// ---------------------------------------------------------------------------
// Kernel 2: gather selected rows of per_point_features -> bf16 [B*K, D]
// ---------------------------------------------------------------------------
__global__ void gather_cast_kernel(const float* __restrict__ feats,
                                   const int* __restrict__ sidx,
                                   __hip_bfloat16* __restrict__ Ag) {
    const int row = blockIdx.x;           // 0..8191
    const int b = row >> 9;
    const int src = sidx[row];
    const float* p = feats + ((size_t)b * PN + (size_t)src) * PD;
    __hip_bfloat16* q = Ag + (size_t)row * PD;
    for (int i = threadIdx.x; i < PD; i += blockDim.x)
        q[i] = __float2bfloat16(p[i]);
}

__global__ void cast_f32_bf16_kernel(const float* __restrict__ src,
                                     __hip_bfloat16* __restrict__ dst, int n) {
    int i = blockIdx.x * blockDim.x + threadIdx.x;
    if (i < n) dst[i] = __float2bfloat16(src[i]);
}

// ---------------------------------------------------------------------------
// Kernel 3: bf16 MFMA GEMM, C[M,N] = A[M,K] * B[N,K]^T + bias.
// Block 256 thr = 4 waves (2x2), wave tile 64x64, block tile 128x128.
// Optional fp32 and bf16 outputs.
// ---------------------------------------------------------------------------
__global__ __launch_bounds__(256) void gemm_bt_bf16_kernel(
    const short* __restrict__ A, const short* __restrict__ Bm,
    const float* __restrict__ bias,
    float* __restrict__ C32, __hip_bfloat16* __restrict__ C16,
    int M, int N, int Kd) {
    const int tid = threadIdx.x;
    const int wave = tid >> 6;
    const int lane = tid & 63;
    const int m0 = blockIdx.x * 128 + (wave >> 1) * 64;
    const int n0 = blockIdx.y * 128 + (wave & 1) * 64;
    const int mrow = lane & 15;
    const int quad = lane >> 4;

    f32x4 acc[4][4] = {};
    for (int k0 = 0; k0 < Kd; k0 += 32) {
        const int kk = k0 + quad * 8;
        bf16x8 a[4], bf[4];
#pragma unroll
        for (int i = 0; i < 4; ++i)
            a[i] = *(const bf16x8*)(A + (size_t)(m0 + i * 16 + mrow) * Kd + kk);
#pragma unroll
        for (int i = 0; i < 4; ++i)
            bf[i] = *(const bf16x8*)(Bm + (size_t)(n0 + i * 16 + mrow) * Kd + kk);
#pragma unroll
        for (int i = 0; i < 4; ++i)
#pragma unroll
            for (int j = 0; j < 4; ++j)
                acc[i][j] = __builtin_amdgcn_mfma_f32_16x16x32_bf16(a[i], bf[j], acc[i][j], 0, 0, 0);
    }
#pragma unroll
    for (int i = 0; i < 4; ++i)
#pragma unroll
        for (int j = 0; j < 4; ++j)
#pragma unroll
            for (int r = 0; r < 4; ++r) {
                int row = m0 + i * 16 + quad * 4 + r;
                int col = n0 + j * 16 + mrow;
                float v = acc[i][j][r] + bias[col];
                if (C32) C32[(size_t)row * N + col] = v;
                if (C16) C16[(size_t)row * N + col] = __float2bfloat16(v);
            }
}

// ---------------------------------------------------------------------------
// Kernel 4: extract the 16 query rows per batch from x (fp32) -> xq [256,512]
// ---------------------------------------------------------------------------
__global__ void extract_xq_kernel(const float* __restrict__ x, float* __restrict__ xq) {
    const int r = blockIdx.x;             // 0..255
    const int b = r >> 4, t = r & 15;
    const float* src = x + ((size_t)b * PK + t) * PE;
    float* dst = xq + (size_t)r * PE;
    for (int i = threadIdx.x; i < PE; i += blockDim.x) dst[i] = src[i];
}

// ---------------------------------------------------------------------------
// Kernel 5: fp32 tiled GEMM, C[M,N] = A[M,K] * B[N,K]^T + bias (small M)
// block 256 thr, tile 32x32, 2x2 per thread.
// ---------------------------------------------------------------------------
__global__ __launch_bounds__(256) void sgemm_bt_kernel(
    const float* __restrict__ A, const float* __restrict__ Bm,
    const float* __restrict__ bias, float* __restrict__ C,
    int M, int N, int Kd) {
    __shared__ float As[32][33];
    __shared__ float Bs[32][33];
    const int tid = threadIdx.x;
    const int m0 = blockIdx.x * 32, n0 = blockIdx.y * 32;
    const int tx = tid & 15, ty = tid >> 4;
    float acc00 = 0, acc01 = 0, acc10 = 0, acc11 = 0;
    for (int k0 = 0; k0 < Kd; k0 += 32) {
        for (int e = tid; e < 1024; e += 256) {
            int r = e >> 5, c = e & 31;
            As[r][c] = A[(size_t)(m0 + r) * Kd + k0 + c];
            Bs[r][c] = Bm[(size_t)(n0 + r) * Kd + k0 + c];
        }
        __syncthreads();
#pragma unroll
        for (int kk = 0; kk < 32; ++kk) {
            float a0 = As[ty * 2][kk], a1 = As[ty * 2 + 1][kk];
            float b0 = Bs[tx * 2][kk], b1 = Bs[tx * 2 + 1][kk];
            acc00 += a0 * b0; acc01 += a0 * b1;
            acc10 += a1 * b0; acc11 += a1 * b1;
        }
        __syncthreads();
    }
    float bc0 = bias[n0 + tx * 2], bc1 = bias[n0 + tx * 2 + 1];
    C[(size_t)(m0 + ty * 2) * N + n0 + tx * 2]         = acc00 + bc0;
    C[(size_t)(m0 + ty * 2) * N + n0 + tx * 2 + 1]     = acc01 + bc1;
    C[(size_t)(m0 + ty * 2 + 1) * N + n0 + tx * 2]     = acc10 + bc0;
    C[(size_t)(m0 + ty * 2 + 1) * N + n0 + tx * 2 + 1] = acc11 + bc1;
}

// ---------------------------------------------------------------------------
// Kernel 6: attention for 16 queries x 512 keys, one block per (b,h).
// q fp32 [256,512]; kv bf16 [8192,1024] (cols 0..511 = k, 512..1023 = v).
// ---------------------------------------------------------------------------
__global__ __launch_bounds__(256) void attn_kernel(
    const float* __restrict__ qb, const __hip_bfloat16* __restrict__ kv,
    float* __restrict__ ob) {
    const int bh = blockIdx.x;
    const int b = bh >> 3, h = bh & 7;
    const int tid = threadIdx.x;
    __shared__ float qs[PT][DH + 1];
    __shared__ float ls[PT][PK + 1];

    for (int i = tid; i < PT * DH; i += 256) {
        int t = i >> 6, d = i & 63;
        qs[t][d] = qb[(size_t)(b * PT + t) * PE + h * DH + d];
    }
    __syncthreads();

    const int t = tid >> 4;
    const int ko = tid & 15;
    for (int k = ko; k < PK; k += 16) {
        const __hip_bfloat16* kp = kv + (size_t)(b * PK + k) * (2 * PE) + h * DH;
        float acc = 0;
#pragma unroll 8
        for (int d = 0; d < DH; ++d) acc += qs[t][d] * __bfloat162float(kp[d]);
        ls[t][k] = acc * 0.125f;
    }
    // softmax over row t (16 threads own the row; all within one wave)
    float m = -1e30f;
    for (int k = ko; k < PK; k += 16) m = fmaxf(m, ls[t][k]);
#pragma unroll
    for (int s = 8; s >= 1; s >>= 1) m = fmaxf(m, __shfl_xor(m, s, 16));
    float sum = 0;
    for (int k = ko; k < PK; k += 16) {
        float e = __expf(ls[t][k] - m);
        ls[t][k] = e;
        sum += e;
    }
#pragma unroll
    for (int s = 8; s >= 1; s >>= 1) sum += __shfl_xor(sum, s, 16);
    const float inv = 1.0f / sum;

    // o = attn @ v ; same 16 threads per row, now covering 4 d's each
    const int dv = tid & 15;
    float o0 = 0, o1 = 0, o2 = 0, o3 = 0;
    for (int k = 0; k < PK; ++k) {
        float w = ls[t][k];
        const __hip_bfloat16* vp = kv + (size_t)(b * PK + k) * (2 * PE) + PE + h * DH;
        o0 += w * __bfloat162float(vp[dv]);
        o1 += w * __bfloat162float(vp[dv + 16]);
        o2 += w * __bfloat162float(vp[dv + 32]);
        o3 += w * __bfloat162float(vp[dv + 48]);
    }
    float* orow = ob + (size_t)(b * PT + t) * PE + h * DH;
    orow[dv]      = o0 * inv;
    orow[dv + 16] = o1 * inv;
    orow[dv + 32] = o2 * inv;
    orow[dv + 48] = o3 * inv;
}

// ---------------------------------------------------------------------------
// Kernel 7: y = LayerNorm(xq + o2) * g + b      (256 rows of 512)
// ---------------------------------------------------------------------------
__global__ __launch_bounds__(256) void ln_kernel(
    const float* __restrict__ xq, const float* __restrict__ o2,
    const float* __restrict__ g, const float* __restrict__ bb,
    float* __restrict__ y) {
    const int r = blockIdx.x;
    const int tid = threadIdx.x;
    __shared__ float red[4], red2[4];
    float v0 = xq[(size_t)r * PE + tid] + o2[(size_t)r * PE + tid];
    float v1 = xq[(size_t)r * PE + 256 + tid] + o2[(size_t)r * PE + 256 + tid];
    float s = v0 + v1;
#pragma unroll
    for (int sh = 32; sh >= 1; sh >>= 1) s += __shfl_xor(s, sh, 64);
    if ((tid & 63) == 0) red[tid >> 6] = s;
    __syncthreads();
    float mean = (red[0] + red[1] + red[2] + red[3]) * (1.0f / 512.0f);
    float d0 = v0 - mean, d1 = v1 - mean;
    float sq = d0 * d0 + d1 * d1;
#pragma unroll
    for (int sh = 32; sh >= 1; sh >>= 1) sq += __shfl_xor(sq, sh, 64);
    if ((tid & 63) == 0) red2[tid >> 6] = sq;
    __syncthreads();
    float var = (red2[0] + red2[1] + red2[2] + red2[3]) * (1.0f / 512.0f);
    float rs = rsqrtf(var + 1e-5f);
    y[(size_t)r * PE + tid]       = d0 * rs * g[tid] + bb[tid];
    y[(size_t)r * PE + 256 + tid] = d1 * rs * g[tid + 256] + bb[tid + 256];
}

// ---------------------------------------------------------------------------
// Kernel 8: out = y + gelu_exact(z)
// ---------------------------------------------------------------------------
__global__ void gelu_res_kernel(const float* __restrict__ y,
                                const float* __restrict__ z,
                                float* __restrict__ out, int n) {
    int i = blockIdx.x * blockDim.x + threadIdx.x;
    if (i < n) {
        float zz = z[i];
        float gl = 0.5f * zz * (1.0f + erff(zz * 0.7071067811865475f));
        out[i] = y[i] + gl;
    }
}

// ---------------------------------------------------------------------------
extern "C" void kernel_launch(void* const* d_in, const int* in_sizes, int n_in,
                              void* d_out, int out_size, void* d_ws, size_t ws_size,
                              hipStream_t stream) {
    const float* feats  = (const float*)d_in[0];
    const float* scores = (const float*)d_in[1];
    const float* proj_w = (const float*)d_in[2];
    const float* proj_b = (const float*)d_in[3];
    const float* in_w   = (const float*)d_in[4];
    const float* in_b   = (const float*)d_in[5];
    const float* out_w  = (const float*)d_in[6];
    const float* out_b  = (const float*)d_in[7];
    const float* ln_g   = (const float*)d_in[8];
    const float* ln_b   = (const float*)d_in[9];
    const float* ffn_w  = (const float*)d_in[10];
    const float* ffn_b  = (const float*)d_in[11];
    float* out = (float*)d_out;

    char* p = (char*)d_ws;
    auto alloc = [&](size_t bytes) {
        void* r = (void*)p;
        p += (bytes + 255) & ~(size_t)255;
        return r;
    };
    int* sidx             = (int*)alloc((size_t)PB * PK * 4);
    __hip_bfloat16* Ag    = (__hip_bfloat16*)alloc((size_t)PB * PK * PD * 2);
    __hip_bfloat16* Wp16  = (__hip_bfloat16*)alloc((size_t)PE * PD * 2);
    __hip_bfloat16* Wkv16 = (__hip_bfloat16*)alloc((size_t)2 * PE * PE * 2);
    float* x32            = (float*)alloc((size_t)PB * PK * PE * 4);
    __hip_bfloat16* x16   = (__hip_bfloat16*)alloc((size_t)PB * PK * PE * 2);
    __hip_bfloat16* kv16  = (__hip_bfloat16*)alloc((size_t)PB * PK * 2 * PE * 2);
    float* xq             = (float*)alloc((size_t)PB * PT * PE * 4);
    float* qb             = (float*)alloc((size_t)PB * PT * PE * 4);
    float* ob             = (float*)alloc((size_t)PB * PT * PE * 4);
    float* o2             = (float*)alloc((size_t)PB * PT * PE * 4);
    float* yb             = (float*)alloc((size_t)PB * PT * PE * 4);
    float* zb             = (float*)alloc((size_t)PB * PT * PE * 4);
    if ((size_t)(p - (char*)d_ws) > ws_size) return;  // workspace too small

    // 1. top-k per batch
    topk_kernel<<<PB, 512, 0, stream>>>(scores, sidx);
    // 2. gather + casts
    gather_cast_kernel<<<PB * PK, 64, 0, stream>>>(feats, sidx, Ag);
    cast_f32_bf16_kernel<<<(PE * PD + 255) / 256, 256, 0, stream>>>(proj_w, Wp16, PE * PD);
    cast_f32_bf16_kernel<<<(2 * PE * PE + 255) / 256, 256, 0, stream>>>(in_w + (size_t)PE * PE, Wkv16, 2 * PE * PE);
    // 3. x = feats @ proj_w^T + proj_b   (M=8192,N=512,K=256), fp32 + bf16 out
    gemm_bt_bf16_kernel<<<dim3(64, 4), 256, 0, stream>>>(
        (const short*)Ag, (const short*)Wp16, proj_b, x32, x16, PB * PK, PE, PD);
    // 4. kv = x @ Wkv^T + bkv           (M=8192,N=1024,K=512), bf16 out only
    gemm_bt_bf16_kernel<<<dim3(64, 8), 256, 0, stream>>>(
        (const short*)x16, (const short*)Wkv16, in_b + PE, nullptr, kv16,
        PB * PK, 2 * PE, PE);
    // 5. query rows
    extract_xq_kernel<<<PB * PT, 256, 0, stream>>>(x32, xq);
    // 6. q = xq @ Wq^T + bq             (M=256,N=512,K=512) fp32
    sgemm_bt_kernel<<<dim3(8, 16), 256, 0, stream>>>(xq, in_w, in_b, qb, PB * PT, PE, PE);
    // 7. attention
    attn_kernel<<<PB * PH, 256, 0, stream>>>(qb, kv16, ob);
    // 8. o2 = o @ out_proj^T + b
    sgemm_bt_kernel<<<dim3(8, 16), 256, 0, stream>>>(ob, out_w, out_b, o2, PB * PT, PE, PE);
    // 9. y = LN(xq + o2)
    ln_kernel<<<PB * PT, 256, 0, stream>>>(xq, o2, ln_g, ln_b, yb);
    // 10. z = y @ ffn_w^T + b
    sgemm_bt_kernel<<<dim3(8, 16), 256, 0, stream>>>(yb, ffn_w, ffn_b, zb, PB * PT, PE, PE);
    // 11. out = y + gelu(z)
    gelu_res_kernel<<<(PB * PT * PE + 255) / 256, 256, 0, stream>>>(yb, zb, out, PB * PT * PE);
}

// Round 2
// 909.017 us; speedup vs baseline: 1.0628x; 1.0628x over previous
//
#include <hip/hip_runtime.h>
#include <hip/hip_bf16.h>
#include <math.h>

// Problem constants
#define PB 16      // batches
#define PN 32768   // points
#define PD 256     // point feature dim
#define PE 512     // embed dim
#define PH 8       // heads
#define PK 512     // top-k
#define PT 16      // output tokens
#define DH 64      // head dim

typedef __attribute__((ext_vector_type(8))) short bf16x8;
typedef __attribute__((ext_vector_type(4))) float f32x4;

__device__ __forceinline__ unsigned short f2bf(float f) {
    __hip_bfloat16 h = __float2bfloat16(f);
    return *(unsigned short*)&h;
}
__device__ __forceinline__ float b2f(unsigned short u) {
    return __uint_as_float(((unsigned int)u) << 16);
}

// ---------------------------------------------------------------------------
// Kernel 1: per-batch top-512 (radix select on monotone u32 keys) + bitonic
// sort by (key desc, idx asc) so first 16 match jax.lax.top_k ordering.
// float4-vectorized scans.
// ---------------------------------------------------------------------------
__global__ __launch_bounds__(512) void topk_kernel(const float* __restrict__ scores,
                                                   int* __restrict__ sorted_idx) {
    const int b = blockIdx.x;
    const int tid = threadIdx.x;
    const int NT = 512;
    const float* s = scores + (size_t)b * PN;

    __shared__ unsigned int hist[256];
    __shared__ unsigned int sh_prefix;
    __shared__ int sh_remaining;
    __shared__ unsigned int sh_cnt_gt, sh_cnt_eq;
    __shared__ unsigned long long comp[PK];
    __shared__ unsigned int eq_idx[PK];

    unsigned int prefix = 0;
    int remaining = PK;
    for (int shift = 24; shift >= 0; shift -= 8) {
        for (int i = tid; i < 256; i += NT) hist[i] = 0;
        __syncthreads();
        for (int i = tid * 4; i < PN; i += NT * 4) {
            float4 f = *(const float4*)(s + i);
            const float* fp = (const float*)&f;
#pragma unroll
            for (int j = 0; j < 4; ++j) {
                unsigned int u = __float_as_uint(fp[j]);
                u = (u & 0x80000000u) ? ~u : (u | 0x80000000u);
                bool ok = (shift == 24) || ((u >> (shift + 8)) == prefix);
                if (ok) atomicAdd(&hist[(u >> shift) & 0xFFu], 1u);
            }
        }
        __syncthreads();
        if (tid == 0) {
            int cum = 0;
            int d = 255;
            for (; d >= 0; --d) {
                cum += (int)hist[d];
                if (cum >= remaining) break;
            }
            sh_remaining = remaining - (cum - (int)hist[d]);
            sh_prefix = (prefix << 8) | (unsigned)d;
        }
        __syncthreads();
        prefix = sh_prefix;
        remaining = sh_remaining;
        __syncthreads();
    }
    const unsigned int TKEY = prefix;

    if (tid == 0) { sh_cnt_gt = 0; sh_cnt_eq = 0; }
    __syncthreads();
    for (int i = tid * 4; i < PN; i += NT * 4) {
        float4 f = *(const float4*)(s + i);
        const float* fp = (const float*)&f;
#pragma unroll
        for (int j = 0; j < 4; ++j) {
            unsigned int u = __float_as_uint(fp[j]);
            u = (u & 0x80000000u) ? ~u : (u | 0x80000000u);
            if (u > TKEY) {
                unsigned p = atomicAdd(&sh_cnt_gt, 1u);
                comp[p] = ((unsigned long long)u << 32) | (unsigned int)(~(unsigned)(i + j));
            } else if (u == TKEY) {
                unsigned p = atomicAdd(&sh_cnt_eq, 1u);
                if (p < PK) eq_idx[p] = (unsigned)(i + j);
            }
        }
    }
    __syncthreads();
    const int cnt_gt = (int)sh_cnt_gt;
    const int need_eq = PK - cnt_gt;
    const int ec = (int)sh_cnt_eq < PK ? (int)sh_cnt_eq : PK;
    if (tid == 0) {
        for (int j = 0; j < need_eq; ++j) {
            unsigned mv = 0xFFFFFFFFu; int mb = 0;
            for (int i2 = 0; i2 < ec; ++i2)
                if (eq_idx[i2] < mv) { mv = eq_idx[i2]; mb = i2; }
            comp[cnt_gt + j] = ((unsigned long long)TKEY << 32) | (unsigned int)(~mv);
            eq_idx[mb] = 0xFFFFFFFFu;
        }
    }
    __syncthreads();

    // bitonic sort, descending (key desc; tie -> ~idx larger = idx smaller first)
    for (unsigned ksz = 2; ksz <= PK; ksz <<= 1) {
        for (unsigned j = ksz >> 1; j > 0; j >>= 1) {
            unsigned i = (unsigned)tid;
            unsigned ixj = i ^ j;
            if (ixj > i && i < PK) {
                unsigned long long a = comp[i], c = comp[ixj];
                bool sw = ((i & ksz) == 0) ? (a < c) : (a > c);
                if (sw) { comp[i] = c; comp[ixj] = a; }
            }
            __syncthreads();
        }
    }
    if (tid < PK)
        sorted_idx[b * PK + tid] = (int)(~(unsigned int)(comp[tid] & 0xFFFFFFFFull));
}

// ---------------------------------------------------------------------------
// Kernel 2: gather selected rows -> bf16 [B*K, D]. 4 rows/block, float4 loads.
// ---------------------------------------------------------------------------
__global__ __launch_bounds__(256) void gather_cast_kernel(const float* __restrict__ feats,
                                                          const int* __restrict__ sidx,
                                                          __hip_bfloat16* __restrict__ Ag) {
    const int row = blockIdx.x * 4 + (threadIdx.x >> 6);   // 2048 blocks
    const int lane = threadIdx.x & 63;
    const int b = row >> 9;
    const int src = sidx[row];
    float4 f = *(const float4*)(feats + ((size_t)b * PN + (size_t)src) * PD + lane * 4);
    ushort4 u;
    u.x = f2bf(f.x); u.y = f2bf(f.y); u.z = f2bf(f.z); u.w = f2bf(f.w);
    *(ushort4*)((unsigned short*)Ag + (size_t)row * PD + lane * 4) = u;
}

// ---------------------------------------------------------------------------
// Kernel 3: fused weight casts (proj_w 512x256, kv part of in_proj 1024x512)
// ---------------------------------------------------------------------------
__global__ __launch_bounds__(256) void cast_weights_kernel(
    const float* __restrict__ proj_w, const float* __restrict__ kv_w,
    __hip_bfloat16* __restrict__ Wp16, __hip_bfloat16* __restrict__ Wkv16) {
    const int n1 = PE * PD / 4;       // 32768 float4s
    const int n2 = 2 * PE * PE / 4;   // 131072 float4s
    int i = blockIdx.x * 256 + threadIdx.x;
    const float4* src;
    unsigned short* dst;
    int off;
    if (i < n1) { src = (const float4*)proj_w; dst = (unsigned short*)Wp16; off = i; }
    else if (i < n1 + n2) { src = (const float4*)kv_w; dst = (unsigned short*)Wkv16; off = i - n1; }
    else return;
    float4 f = src[off];
    ushort4 u;
    u.x = f2bf(f.x); u.y = f2bf(f.y); u.z = f2bf(f.z); u.w = f2bf(f.w);
    *(ushort4*)(dst + (size_t)off * 4) = u;
}

// ---------------------------------------------------------------------------
// Kernel 4: bf16 MFMA GEMM, C[M,N] = A[M,K]*B[N,K]^T + bias.
// Block 256 thr = 4 waves (2x2), wave tile 64x64, block tile 128x128.
// Outputs: bf16 C16 (full) and/or compacted fp32 Xq (rows with (row&511)<PT).
// ---------------------------------------------------------------------------
__global__ __launch_bounds__(256) void gemm_bt_bf16_kernel(
    const short* __restrict__ A, const short* __restrict__ Bm,
    const float* __restrict__ bias,
    __hip_bfloat16* __restrict__ C16, float* __restrict__ Xq,
    int M, int N, int Kd) {
    const int tid = threadIdx.x;
    const int wave = tid >> 6;
    const int lane = tid & 63;
    const int m0 = blockIdx.x * 128 + (wave >> 1) * 64;
    const int n0 = blockIdx.y * 128 + (wave & 1) * 64;
    const int mrow = lane & 15;
    const int quad = lane >> 4;

    f32x4 acc[4][4] = {};
    for (int k0 = 0; k0 < Kd; k0 += 32) {
        const int kk = k0 + quad * 8;
        bf16x8 a[4], bf[4];
#pragma unroll
        for (int i = 0; i < 4; ++i)
            a[i] = *(const bf16x8*)(A + (size_t)(m0 + i * 16 + mrow) * Kd + kk);
#pragma unroll
        for (int i = 0; i < 4; ++i)
            bf[i] = *(const bf16x8*)(Bm + (size_t)(n0 + i * 16 + mrow) * Kd + kk);
#pragma unroll
        for (int i = 0; i < 4; ++i)
#pragma unroll
            for (int j = 0; j < 4; ++j)
                acc[i][j] = __builtin_amdgcn_mfma_f32_16x16x32_bf16(a[i], bf[j], acc[i][j], 0, 0, 0);
    }
#pragma unroll
    for (int i = 0; i < 4; ++i)
#pragma unroll
        for (int j = 0; j < 4; ++j)
#pragma unroll
            for (int r = 0; r < 4; ++r) {
                int row = m0 + i * 16 + quad * 4 + r;
                int col = n0 + j * 16 + mrow;
                float v = acc[i][j][r] + bias[col];
                if (C16) {
                    __hip_bfloat16 hv = __float2bfloat16(v);
                    ((__hip_bfloat16*)C16)[(size_t)row * N + col] = hv;
                }
                if (Xq) {
                    int t = row & (PK - 1);     // wave-uniform predicate (16-row tiles)
                    if (t < PT)
                        Xq[((size_t)(row >> 9) * PT + t) * N + col] = v;
                }
            }
}

// ---------------------------------------------------------------------------
// Kernel 5: fp32 tiled GEMM, C[M,N] = A[M,K]*B[N,K]^T + bias, optional fused
// exact-GELU + residual epilogue (resid != nullptr):  C = resid + gelu(acc+b)
// ---------------------------------------------------------------------------
__global__ __launch_bounds__(256) void sgemm_bt_kernel(
    const float* __restrict__ A, const float* __restrict__ Bm,
    const float* __restrict__ bias, const float* __restrict__ resid,
    float* __restrict__ C, int M, int N, int Kd) {
    __shared__ float As[32][33];
    __shared__ float Bs[32][33];
    const int tid = threadIdx.x;
    const int m0 = blockIdx.x * 32, n0 = blockIdx.y * 32;
    const int tx = tid & 15, ty = tid >> 4;
    float acc00 = 0, acc01 = 0, acc10 = 0, acc11 = 0;
    for (int k0 = 0; k0 < Kd; k0 += 32) {
        for (int e = tid; e < 1024; e += 256) {
            int r = e >> 5, c = e & 31;
            As[r][c] = A[(size_t)(m0 + r) * Kd + k0 + c];
            Bs[r][c] = Bm[(size_t)(n0 + r) * Kd + k0 + c];
        }
        __syncthreads();
#pragma unroll
        for (int kk = 0; kk < 32; ++kk) {
            float a0 = As[ty * 2][kk], a1 = As[ty * 2 + 1][kk];
            float b0 = Bs[tx * 2][kk], b1 = Bs[tx * 2 + 1][kk];
            acc00 += a0 * b0; acc01 += a0 * b1;
            acc10 += a1 * b0; acc11 += a1 * b1;
        }
        __syncthreads();
    }
    float bc0 = bias[n0 + tx * 2], bc1 = bias[n0 + tx * 2 + 1];
    float v00 = acc00 + bc0, v01 = acc01 + bc1, v10 = acc10 + bc0, v11 = acc11 + bc1;
    size_t i00 = (size_t)(m0 + ty * 2) * N + n0 + tx * 2;
    size_t i10 = (size_t)(m0 + ty * 2 + 1) * N + n0 + tx * 2;
    if (resid) {
        v00 = resid[i00]     + 0.5f * v00 * (1.0f + erff(v00 * 0.7071067811865475f));
        v01 = resid[i00 + 1] + 0.5f * v01 * (1.0f + erff(v01 * 0.7071067811865475f));
        v10 = resid[i10]     + 0.5f * v10 * (1.0f + erff(v10 * 0.7071067811865475f));
        v11 = resid[i10 + 1] + 0.5f * v11 * (1.0f + erff(v11 * 0.7071067811865475f));
    }
    C[i00] = v00; C[i00 + 1] = v01;
    C[i10] = v10; C[i10 + 1] = v11;
}

// ---------------------------------------------------------------------------
// Kernel 6: attention, one block per (b,h): 16 queries x 512 keys x 64 dims.
// q fp32 [256,512]; kv bf16 [8192,1024] (cols 0..511 = k, 512..1023 = v).
// All sharing is intra-wave (t-groups of 16 lanes), vectorized ushort4 loads.
// ---------------------------------------------------------------------------
__global__ __launch_bounds__(256) void attn_kernel(
    const float* __restrict__ qb, const __hip_bfloat16* __restrict__ kv,
    float* __restrict__ ob) {
    const int bh = blockIdx.x;
    const int b = bh >> 3, h = bh & 7;
    const int tid = threadIdx.x;
    __shared__ float qs[PT][DH + 4];
    __shared__ float ls[PT][PK + 1];

    {   // vectorized q load: 1024 floats / 256 threads = 1 float4 each
        int i4 = tid * 4;
        int t = i4 >> 6, d = i4 & 63;
        float4 f = *(const float4*)(qb + (size_t)(b * PT + t) * PE + h * DH + d);
        qs[t][d] = f.x; qs[t][d + 1] = f.y; qs[t][d + 2] = f.z; qs[t][d + 3] = f.w;
    }
    __syncthreads();

    const int t = tid >> 4;
    const int ko = tid & 15;
    for (int k = ko; k < PK; k += 16) {
        const ushort4* kp = (const ushort4*)((const unsigned short*)kv +
                             (size_t)(b * PK + k) * (2 * PE) + h * DH);
        float acc = 0;
#pragma unroll
        for (int c = 0; c < 16; ++c) {
            ushort4 vv = kp[c];
            acc += qs[t][c * 4 + 0] * b2f(vv.x) + qs[t][c * 4 + 1] * b2f(vv.y)
                 + qs[t][c * 4 + 2] * b2f(vv.z) + qs[t][c * 4 + 3] * b2f(vv.w);
        }
        ls[t][k] = acc * 0.125f;
    }
    // softmax over row t: the 16 owning lanes are in one wave
    float m = -1e30f;
    for (int k = ko; k < PK; k += 16) m = fmaxf(m, ls[t][k]);
#pragma unroll
    for (int s = 8; s >= 1; s >>= 1) m = fmaxf(m, __shfl_xor(m, s, 16));
    float sum = 0;
    for (int k = ko; k < PK; k += 16) {
        float e = __expf(ls[t][k] - m);
        ls[t][k] = e;
        sum += e;
    }
#pragma unroll
    for (int s = 8; s >= 1; s >>= 1) sum += __shfl_xor(sum, s, 16);
    const float inv = 1.0f / sum;

    // o = attn @ v ; thread owns 4 consecutive d's -> one 8B load per k
    const int d0 = (tid & 15) * 4;
    const unsigned short* vbase = (const unsigned short*)kv +
                                  (size_t)(b * PK) * (2 * PE) + PE + h * DH + d0;
    float o0 = 0, o1 = 0, o2 = 0, o3 = 0;
#pragma unroll 4
    for (int k = 0; k < PK; ++k) {
        float w = ls[t][k];
        ushort4 vv = *(const ushort4*)(vbase + (size_t)k * (2 * PE));
        o0 += w * b2f(vv.x); o1 += w * b2f(vv.y);
        o2 += w * b2f(vv.z); o3 += w * b2f(vv.w);
    }
    float4 o; o.x = o0 * inv; o.y = o1 * inv; o.z = o2 * inv; o.w = o3 * inv;
    *(float4*)(ob + (size_t)(b * PT + t) * PE + h * DH + d0) = o;
}

// ---------------------------------------------------------------------------
// Kernel 7: y = LayerNorm(xq + o2) * g + b      (256 rows of 512)
// ---------------------------------------------------------------------------
__global__ __launch_bounds__(256) void ln_kernel(
    const float* __restrict__ xq, const float* __restrict__ o2,
    const float* __restrict__ g, const float* __restrict__ bb,
    float* __restrict__ y) {
    const int r = blockIdx.x;
    const int tid = threadIdx.x;
    __shared__ float red[4], red2[4];
    float v0 = xq[(size_t)r * PE + tid] + o2[(size_t)r * PE + tid];
    float v1 = xq[(size_t)r * PE + 256 + tid] + o2[(size_t)r * PE + 256 + tid];
    float s = v0 + v1;
#pragma unroll
    for (int sh = 32; sh >= 1; sh >>= 1) s += __shfl_xor(s, sh, 64);
    if ((tid & 63) == 0) red[tid >> 6] = s;
    __syncthreads();
    float mean = (red[0] + red[1] + red[2] + red[3]) * (1.0f / 512.0f);
    float d0 = v0 - mean, d1 = v1 - mean;
    float sq = d0 * d0 + d1 * d1;
#pragma unroll
    for (int sh = 32; sh >= 1; sh >>= 1) sq += __shfl_xor(sq, sh, 64);
    if ((tid & 63) == 0) red2[tid >> 6] = sq;
    __syncthreads();
    float var = (red2[0] + red2[1] + red2[2] + red2[3]) * (1.0f / 512.0f);
    float rs = rsqrtf(var + 1e-5f);
    y[(size_t)r * PE + tid]       = d0 * rs * g[tid] + bb[tid];
    y[(size_t)r * PE + 256 + tid] = d1 * rs * g[tid + 256] + bb[tid + 256];
}

// ---------------------------------------------------------------------------
extern "C" void kernel_launch(void* const* d_in, const int* in_sizes, int n_in,
                              void* d_out, int out_size, void* d_ws, size_t ws_size,
                              hipStream_t stream) {
    const float* feats  = (const float*)d_in[0];
    const float* scores = (const float*)d_in[1];
    const float* proj_w = (const float*)d_in[2];
    const float* proj_b = (const float*)d_in[3];
    const float* in_w   = (const float*)d_in[4];
    const float* in_b   = (const float*)d_in[5];
    const float* out_w  = (const float*)d_in[6];
    const float* out_b  = (const float*)d_in[7];
    const float* ln_g   = (const float*)d_in[8];
    const float* ln_b   = (const float*)d_in[9];
    const float* ffn_w  = (const float*)d_in[10];
    const float* ffn_b  = (const float*)d_in[11];
    float* out = (float*)d_out;

    char* p = (char*)d_ws;
    auto alloc = [&](size_t bytes) {
        void* r = (void*)p;
        p += (bytes + 255) & ~(size_t)255;
        return r;
    };
    int* sidx             = (int*)alloc((size_t)PB * PK * 4);
    __hip_bfloat16* Ag    = (__hip_bfloat16*)alloc((size_t)PB * PK * PD * 2);
    __hip_bfloat16* Wp16  = (__hip_bfloat16*)alloc((size_t)PE * PD * 2);
    __hip_bfloat16* Wkv16 = (__hip_bfloat16*)alloc((size_t)2 * PE * PE * 2);
    __hip_bfloat16* x16   = (__hip_bfloat16*)alloc((size_t)PB * PK * PE * 2);
    __hip_bfloat16* kv16  = (__hip_bfloat16*)alloc((size_t)PB * PK * 2 * PE * 2);
    float* xq             = (float*)alloc((size_t)PB * PT * PE * 4);
    float* qb             = (float*)alloc((size_t)PB * PT * PE * 4);
    float* ob             = (float*)alloc((size_t)PB * PT * PE * 4);
    float* o2             = (float*)alloc((size_t)PB * PT * PE * 4);
    float* yb             = (float*)alloc((size_t)PB * PT * PE * 4);
    if ((size_t)(p - (char*)d_ws) > ws_size) return;  // workspace too small

    // 1. top-k per batch
    topk_kernel<<<PB, 512, 0, stream>>>(scores, sidx);
    // 2. gather + weight casts
    gather_cast_kernel<<<PB * PK / 4, 256, 0, stream>>>(feats, sidx, Ag);
    {
        int nvec = (PE * PD + 2 * PE * PE) / 4;
        cast_weights_kernel<<<(nvec + 255) / 256, 256, 0, stream>>>(
            proj_w, in_w + (size_t)PE * PE, Wp16, Wkv16);
    }
    // 3. x = feats @ proj_w^T + proj_b   (M=8192,N=512,K=256) -> x16 + xq
    gemm_bt_bf16_kernel<<<dim3(64, 4), 256, 0, stream>>>(
        (const short*)Ag, (const short*)Wp16, proj_b, x16, xq, PB * PK, PE, PD);
    // 4. kv = x @ Wkv^T + bkv            (M=8192,N=1024,K=512) -> kv16
    gemm_bt_bf16_kernel<<<dim3(64, 8), 256, 0, stream>>>(
        (const short*)x16, (const short*)Wkv16, in_b + PE, kv16, nullptr,
        PB * PK, 2 * PE, PE);
    // 5. q = xq @ Wq^T + bq              (M=256,N=512,K=512) fp32
    sgemm_bt_kernel<<<dim3(8, 16), 256, 0, stream>>>(xq, in_w, in_b, nullptr, qb, PB * PT, PE, PE);
    // 6. attention
    attn_kernel<<<PB * PH, 256, 0, stream>>>(qb, kv16, ob);
    // 7. o2 = o @ out_proj^T + b
    sgemm_bt_kernel<<<dim3(8, 16), 256, 0, stream>>>(ob, out_w, out_b, nullptr, o2, PB * PT, PE, PE);
    // 8. y = LN(xq + o2)
    ln_kernel<<<PB * PT, 256, 0, stream>>>(xq, o2, ln_g, ln_b, yb);
    // 9. out = y + gelu(y @ ffn_w^T + b)  (fused epilogue, writes d_out)
    sgemm_bt_kernel<<<dim3(8, 16), 256, 0, stream>>>(yb, ffn_w, ffn_b, yb, out, PB * PT, PE, PE);
}